// Round 8
// baseline (91.942 us; speedup 1.0000x reference)
//
#include <hip/hip_runtime.h>

// CategoryDense: out[b,c,o] = sum_i x[b,c,i] * kernel[c,i,o] + bias[c,o]
// B=8192, C=64, IN=64, OUT=64, fp32 in/out. bf16 MFMA (swapped operands),
// fp32 accum.
//
// Structure: block = (category c, 512-batch tile), 4 waves, grid=1024
// (4 blocks/CU). k[c] staged once -> bf16 LDS (8KB) -> k-frags hoisted to
// registers (amortized over 2 batch iterations). x loads go DIRECTLY
// global->reg in B-fragment shape (lane reads 32B contiguous; a wave covers
// 16 full 128B lines) — no x LDS, no x barrier. Plain f32x4 stores
// (R6 evidence: nontemporal caused 41MB write amplification).

constexpr int C_   = 64;
constexpr int IN_  = 64;
constexpr int OUT_ = 64;
constexpr int BT   = 512;   // batches per block (2 iterations of 256)

typedef __attribute__((ext_vector_type(8))) short bf16x8;
typedef __attribute__((ext_vector_type(4))) short s16x4;
typedef __attribute__((ext_vector_type(4))) float f32x4;

__device__ __forceinline__ short f2bf(float f) {
    union { float f; unsigned u; } v; v.f = f;
    unsigned r = v.u + 0x7FFF + ((v.u >> 16) & 1);   // RNE
    return (short)(r >> 16);
}

__device__ __forceinline__ bf16x8 cvt8(f32x4 lo, f32x4 hi) {
    bf16x8 r;
    #pragma unroll
    for (int e = 0; e < 4; ++e) {
        r[e]     = f2bf(lo[e]);
        r[4 + e] = f2bf(hi[e]);
    }
    return r;
}

__global__ __launch_bounds__(256, 4)
void cat_dense_mfma4(const float* __restrict__ x,
                     const float* __restrict__ k,
                     const float* __restrict__ bias,
                     float* __restrict__ out) {
    __shared__ unsigned short ksb[IN_ * OUT_];   // 8 KB bf16, linear [i][o]

    const int tid  = threadIdx.x;
    const int wv   = tid >> 6;
    const int lane = tid & 63;
    const int c    = blockIdx.x & 63;
    const long bBase = (long)(blockIdx.x >> 6) * BT;

    const int lrow = lane & 15;   // B col = batch row; A row = out channel
    const int lkg  = lane >> 4;   // K-octet select; C row-group

    // ---- stage k[c] -> bf16 LDS (linear, coalesced) ----
    #pragma unroll
    for (int it = 0; it < 4; ++it) {
        int p = tid + it * 256;
        f32x4 v = *(const f32x4*)(k + (size_t)c * (IN_ * OUT_) + (size_t)p * 4);
        s16x4 w;
        #pragma unroll
        for (int e = 0; e < 4; ++e) w[e] = f2bf(v[e]);
        *(s16x4*)(&ksb[p * 4]) = w;
    }

    // bias: lane's 4 consecutive output cols per nt
    f32x4 bv[4];
    #pragma unroll
    for (int nt = 0; nt < 4; ++nt)
        bv[nt] = *(const f32x4*)(bias + (size_t)c * OUT_ + nt * 16 + lkg * 4);

    __syncthreads();   // only barrier: k staged

    // ---- kT A-fragments hoisted to registers (one-time per block) ----
    // A[row=o=nt*16+lrow][k=i=ksi*32+lkg*8+j]
    bf16x8 kb[4][2];
    #pragma unroll
    for (int nt = 0; nt < 4; ++nt)
      #pragma unroll
      for (int ksi = 0; ksi < 2; ++ksi) {
        union { bf16x8 v; short s[8]; } b;
        #pragma unroll
        for (int j = 0; j < 8; ++j)
            b.s[j] = (short)ksb[(ksi * 32 + lkg * 8 + j) * OUT_ + nt * 16 + lrow];
        kb[nt][ksi] = b.v;
      }

    // ---- 2 batch iterations of 256 (64 per wave) ----
    #pragma unroll
    for (int t = 0; t < 2; ++t) {
        const long rw = bBase + t * 256 + wv * 64;

        // xT B-fragments direct from global: lane reads 32B contiguous
        bf16x8 af[2][2][2];   // [p][mt][ksi]
        #pragma unroll
        for (int p = 0; p < 2; ++p)
          #pragma unroll
          for (int mt = 0; mt < 2; ++mt)
            #pragma unroll
            for (int ksi = 0; ksi < 2; ++ksi) {
                const float* xp = x
                    + (size_t)(rw + p * 32 + mt * 16 + lrow) * (C_ * IN_)
                    + (size_t)c * IN_ + ksi * 32 + lkg * 8;
                f32x4 lo = *(const f32x4*)xp;
                f32x4 hi = *(const f32x4*)(xp + 4);
                af[p][mt][ksi] = cvt8(lo, hi);
            }

        #pragma unroll
        for (int p = 0; p < 2; ++p) {
            f32x4 acc[2][4];
            #pragma unroll
            for (int mt = 0; mt < 2; ++mt)
              #pragma unroll
              for (int nt = 0; nt < 4; ++nt)
                acc[mt][nt] = (f32x4){0.f, 0.f, 0.f, 0.f};

            #pragma unroll
            for (int ksi = 0; ksi < 2; ++ksi)
              #pragma unroll
              for (int mt = 0; mt < 2; ++mt)
                #pragma unroll
                for (int nt = 0; nt < 4; ++nt)
                    acc[mt][nt] = __builtin_amdgcn_mfma_f32_16x16x32_bf16(
                                      kb[nt][ksi], af[p][mt][ksi],
                                      acc[mt][nt], 0, 0, 0);

            // D'[row=o'=lkg*4+reg][col=batch=lrow] -> f32x4 store of 4
            // consecutive output channels
            #pragma unroll
            for (int mt = 0; mt < 2; ++mt) {
                size_t rbase = (size_t)(rw + p * 32 + mt * 16 + lrow)
                                   * (C_ * OUT_)
                             + (size_t)c * OUT_ + lkg * 4;
                #pragma unroll
                for (int nt = 0; nt < 4; ++nt) {
                    f32x4 o = acc[mt][nt] + bv[nt];
                    *(f32x4*)(out + rbase + nt * 16) = o;
                }
            }
        }
    }
}

extern "C" void kernel_launch(void* const* d_in, const int* in_sizes, int n_in,
                              void* d_out, int out_size, void* d_ws, size_t ws_size,
                              hipStream_t stream) {
    const float* x    = (const float*)d_in[0];
    const float* k    = (const float*)d_in[1];
    const float* bias = (const float*)d_in[2];
    float* out        = (float*)d_out;

    const int B     = in_sizes[0] / (C_ * IN_);   // 8192
    const int tiles = B / BT;                     // 16
    dim3 grid(64 * tiles);                        // 1024: c = blk & 63
    cat_dense_mfma4<<<grid, 256, 0, stream>>>(x, k, bias, out);
}